// Round 8
// baseline (346.509 us; speedup 1.0000x reference)
//
#include <hip/hip_runtime.h>

#define N_NODES 50000
#define N_EDGES 800000
#define SCAN_BLOCKS 196          // ceil(50000/256)
#define WIN 6250                 // dst window per XCD group (50000/8)

typedef __attribute__((ext_vector_type(8))) short short8;
typedef __attribute__((ext_vector_type(4))) float f32x4;
typedef __attribute__((ext_vector_type(2))) float f32x2;
typedef unsigned short ushort_t;
typedef unsigned int uint_t;

// ---------------- helpers ----------------
__device__ inline ushort_t f2bf(float f) {
    union { float f; uint_t u; } v; v.f = f;
    uint_t u = v.u;
    u += 0x7fffu + ((u >> 16) & 1u);   // RNE
    return (ushort_t)(u >> 16);
}
__device__ inline uint_t packbf(float a, float b) {
    return (uint_t)f2bf(a) | ((uint_t)f2bf(b) << 16);
}
// decode 4 fp8(e4m3) packed in a uint -> acc[0..3] += vals (HW cvt, 2/op)
__device__ inline void acc_fp8x4(uint_t u, float* a) {
    f32x2 p0 = __builtin_amdgcn_cvt_pk_f32_fp8(u, false);
    f32x2 p1 = __builtin_amdgcn_cvt_pk_f32_fp8(u, true);
    a[0] += p0.x; a[1] += p0.y; a[2] += p1.x; a[3] += p1.y;
}
__device__ inline void acc_fp8x16(uint4 v, float* a) {
    acc_fp8x4(v.x, a); acc_fp8x4(v.y, a + 4);
    acc_fp8x4(v.z, a + 8); acc_fp8x4(v.w, a + 12);
}
__device__ inline unsigned char f2fp8(float f) {
    return (unsigned char)(__builtin_amdgcn_cvt_pk_fp8_f32(f, f, 0, false) & 0xff);
}

// ---------------- prep: cvt x->bf16 + x->fp8, pack 3 weight sets, zero cnt ----------------
__global__ void prep(const float* __restrict__ x, uint_t* __restrict__ x_bf_u,
                     uint_t* __restrict__ x_f8_u,
                     const float* __restrict__ Wl0, const float* __restrict__ Wr0,
                     const float* __restrict__ Wl1, const float* __restrict__ Wr1,
                     const float* __restrict__ Wl2, const float* __restrict__ Wr2,
                     ushort_t* __restrict__ pk0, ushort_t* __restrict__ pk1,
                     ushort_t* __restrict__ pkz, int* __restrict__ cnt) {
    int b = blockIdx.x, tid = threadIdx.x;
    if (b < 6250) {                                    // cvt: 1.6M float4
        int i = b * 256 + tid;
        float4 v = ((const float4*)x)[i];
        x_bf_u[i * 2] = packbf(v.x, v.y);
        x_bf_u[i * 2 + 1] = packbf(v.z, v.w);
        uint_t u = __builtin_amdgcn_cvt_pk_fp8_f32(v.x, v.y, 0, false);
        u = __builtin_amdgcn_cvt_pk_fp8_f32(v.z, v.w, u, true);
        x_f8_u[i] = u;
    } else if (b < 6506) {                             // pack pk0 / pk1 (32768 each)
        int bb = b - 6250;
        const float* Wl = (bb < 128) ? Wl0 : Wl1;
        const float* Wr = (bb < 128) ? Wr0 : Wr1;
        ushort_t* out = (bb < 128) ? pk0 : pk1;
        int idx = (bb & 127) * 256 + tid;
        int j = idx & 7, l = (idx >> 3) & 63, t = (idx >> 9) & 7, ks = idx >> 12;
        int n = t * 16 + (l & 15);
        int k = ks * 32 + (l >> 4) * 8 + j;
        float w = (k < 128) ? Wl[k * 128 + n] : Wr[(k - 128) * 128 + n];
        out[idx] = f2bf(w);
    } else if (b < 6570) {                             // pack pkz (16384)
        int idx = (b - 6506) * 256 + tid;
        int j = idx & 7, l = (idx >> 3) & 63, t = (idx >> 9) & 7, ks = idx >> 12;
        int n = t * 16 + (l & 15);
        int k = ks * 32 + (l >> 4) * 8 + j;
        float w = (n < 64) ? Wl2[k * 64 + n] : Wr2[k * 64 + (n - 64)];
        pkz[idx] = f2bf(w);
    } else {                                           // zero cnt: 12500 int4
        int i = (b - 6570) * 256 + tid;
        if (i < 12500) ((int4*)cnt)[i] = make_int4(0, 0, 0, 0);
    }
}

// ---------------- CSR build: XCD-windowed counting sort ----------------
__global__ void count_edges_mp(const int* __restrict__ ei, int* __restrict__ cnt) {
    int g = blockIdx.x & 7;
    int nb = gridDim.x >> 3;
    int bi = blockIdx.x >> 3;
    int lo = g * WIN;
    for (int e = bi * 256 + threadIdx.x; e < N_EDGES; e += nb * 256) {
        int d = ei[N_EDGES + e];
        if ((unsigned)(d - lo) < WIN) atomicAdd(&cnt[d], 1);
    }
}

__global__ void fill_csr_mp(const int* __restrict__ ei, int* __restrict__ cursor,
                            int* __restrict__ csr_src) {
    int g = blockIdx.x & 7;
    int nb = gridDim.x >> 3;
    int bi = blockIdx.x >> 3;
    int lo = g * WIN;
    for (int e = bi * 256 + threadIdx.x; e < N_EDGES; e += nb * 256) {
        int d = ei[N_EDGES + e];
        if ((unsigned)(d - lo) < WIN) {
            int p = atomicAdd(&cursor[d], 1);
            csr_src[p] = ei[e];
        }
    }
}

// ---------------- one-kernel exclusive scan ----------------
__global__ void scan_all(const int* __restrict__ cnt, int* __restrict__ rowstart,
                         int* __restrict__ cursor) {
    __shared__ int s[256];
    __shared__ int wsum[4];
    int t = threadIdx.x, b = blockIdx.x;
    int base = b * 256;
    int pre = 0;
    for (int i = t; i < base; i += 256) pre += cnt[i];
    for (int off = 32; off; off >>= 1) pre += __shfl_down(pre, off, 64);
    if ((t & 63) == 0) wsum[t >> 6] = pre;
    __syncthreads();
    int prefix_base = wsum[0] + wsum[1] + wsum[2] + wsum[3];
    int i = base + t;
    int v = (i < N_NODES) ? cnt[i] : 0;
    s[t] = v;
    __syncthreads();
    for (int off = 1; off < 256; off <<= 1) {
        int add = (t >= off) ? s[t - off] : 0;
        __syncthreads();
        s[t] += add;
        __syncthreads();
    }
    int excl = s[t] - v + prefix_base;
    if (i < N_NODES) { rowstart[i] = excl; cursor[i] = excl; }
    if (b == 0 && t == 0) rowstart[N_NODES] = N_EDGES;
}

// ---------------- fp8 gather: 128B rows, uint4/lane, 8 edges per load ----------------
// chunk = lane&7 (8 uint4 = 128B row), esel = lane>>3. After xor-reduce (8,16,32)
// lanes 0..7 hold dims chunk*16 .. chunk*16+15.
__device__ inline void gather_mean_fp8_128(const uint4* __restrict__ base,
                                           const int* __restrict__ rowstart,
                                           const int* __restrict__ csr,
                                           int node, int lane, float* acc) {
    int s0 = rowstart[node], s1 = rowstart[node + 1];
    int chunk = lane & 7, esel = lane >> 3;
    for (int b = s0; b < s1; b += 64) {
        int m = min(64, s1 - b);
        int idx = (lane < m) ? csr[b + lane] : 0;
        int j = 0;
        for (; j + 16 <= m; j += 16) {
            int i0 = __shfl(idx, j + esel, 64);
            int i1 = __shfl(idx, j + 8 + esel, 64);
            uint4 v0 = base[(size_t)i0 * 8 + chunk];
            uint4 v1 = base[(size_t)i1 * 8 + chunk];
            acc_fp8x16(v0, acc);
            acc_fp8x16(v1, acc);
        }
        for (; j < m; j += 8) {
            int e = j + esel;
            int s = __shfl(idx, min(e, m - 1), 64);
            if (e < m) {
                uint4 v = base[(size_t)s * 8 + chunk];
                acc_fp8x16(v, acc);
            }
        }
    }
    float inv = 1.0f / fmaxf((float)(s1 - s0), 1.0f);
    #pragma unroll
    for (int k = 0; k < 16; ++k) {
        acc[k] += __shfl_xor(acc[k], 8, 64);
        acc[k] += __shfl_xor(acc[k], 16, 64);
        acc[k] += __shfl_xor(acc[k], 32, 64);
        acc[k] *= inv;
    }
}

// ---------------- fused layer: 16 nodes/block, 8 waves, 2 nodes/wave ----------------
// gather fp8 rows -> bf16 A-tile in LDS; MFMA col-tile = wave; root operand bf16.
// CHAIN: h2 = relu(gemm1) kept in LDS, chained into gemm2 -> [z(fp8) | r(f32)].
template <bool CHAIN>
__global__ __launch_bounds__(512, 4) void layer_fused(
    const uint4* __restrict__ gsrc_f8, const ushort_t* __restrict__ root,
    const int* __restrict__ rowstart, const int* __restrict__ csr_src,
    const ushort_t* __restrict__ Bpk, const float* __restrict__ bias1,
    const ushort_t* __restrict__ Bpkz, const float* __restrict__ bias2,
    ushort_t* __restrict__ h_out, unsigned char* __restrict__ h_out_f8,
    unsigned char* __restrict__ z_f8, float* __restrict__ r_f32) {
    __shared__ __align__(16) ushort_t At[16 * 136];
    int lane = threadIdx.x & 63, wave = threadIdx.x >> 6;
    int nodeBase = blockIdx.x * 16;
    int chunk = lane & 7;

    #pragma unroll
    for (int i = 0; i < 2; ++i) {
        int m = wave * 2 + i;
        int node = nodeBase + m;
        float acc[16];
        #pragma unroll
        for (int k = 0; k < 16; ++k) acc[k] = 0.f;
        if (node < N_NODES)
            gather_mean_fp8_128(gsrc_f8, rowstart, csr_src, node, lane, acc);
        if (lane < 8) {
            uint4 w0, w1;
            w0.x = packbf(acc[0], acc[1]);  w0.y = packbf(acc[2], acc[3]);
            w0.z = packbf(acc[4], acc[5]);  w0.w = packbf(acc[6], acc[7]);
            w1.x = packbf(acc[8], acc[9]);  w1.y = packbf(acc[10], acc[11]);
            w1.z = packbf(acc[12], acc[13]); w1.w = packbf(acc[14], acc[15]);
            *(uint4*)&At[m * 136 + chunk * 16] = w0;
            *(uint4*)&At[m * 136 + chunk * 16 + 8] = w1;
        }
    }
    __syncthreads();

    int row16 = lane & 15, quad = lane >> 4;
    const short8* bp = (const short8*)Bpk + lane;
    int rootRow = min(nodeBase + row16, N_NODES - 1);
    const ushort_t* rrow = root + (size_t)rootRow * 128;

    f32x4 acc1 = {0.f, 0.f, 0.f, 0.f};
    #pragma unroll
    for (int ks = 0; ks < 8; ++ks) {
        short8 afrag;
        if (ks < 4) afrag = *(const short8*)&At[row16 * 136 + ks * 32 + quad * 8];
        else        afrag = *(const short8*)(rrow + (ks - 4) * 32 + quad * 8);
        short8 bfrag = bp[(ks * 8 + wave) * 64];
        acc1 = __builtin_amdgcn_mfma_f32_16x16x32_bf16(afrag, bfrag, acc1, 0, 0, 0);
    }

    int col = wave * 16 + row16;
    if (!CHAIN) {
        float bv = bias1[col];
        #pragma unroll
        for (int r = 0; r < 4; ++r) {
            int row = nodeBase + quad * 4 + r;
            if (row < N_NODES) {
                float v = fmaxf(acc1[r] + bv, 0.f);
                h_out[(size_t)row * 128 + col] = f2bf(v);
                h_out_f8[(size_t)row * 128 + col] = f2fp8(v);
            }
        }
    } else {
        __syncthreads();   // all A-tile reads done before overwrite
        float bv = bias1[col];
        #pragma unroll
        for (int r = 0; r < 4; ++r) {
            float v = fmaxf(acc1[r] + bv, 0.f);
            At[(quad * 4 + r) * 136 + col] = f2bf(v);   // h2 tile
        }
        __syncthreads();

        const short8* bpz = (const short8*)Bpkz + lane;
        f32x4 acc2 = {0.f, 0.f, 0.f, 0.f};
        #pragma unroll
        for (int ks = 0; ks < 4; ++ks) {
            short8 afrag = *(const short8*)&At[row16 * 136 + ks * 32 + quad * 8];
            short8 bfrag = bpz[(ks * 8 + wave) * 64];
            acc2 = __builtin_amdgcn_mfma_f32_16x16x32_bf16(afrag, bfrag, acc2, 0, 0, 0);
        }

        #pragma unroll
        for (int r = 0; r < 4; ++r) {
            int row = nodeBase + quad * 4 + r;
            if (row < N_NODES) {
                if (col < 64) z_f8[(size_t)row * 64 + col] = f2fp8(acc2[r]);
                else          r_f32[(size_t)row * 64 + (col - 64)] = acc2[r] + bias2[col - 64];
            }
        }
    }
}

// ---------------- final: fp8 gather (64B rows, 16 edges/load) + log_softmax ----------------
// chunk = lane&3 (4 uint4 = 64B row), esel = lane>>2. After xor-reduce (4,8,16,32)
// lanes 0..3 hold dims chunk*16 .. +15.
__global__ void final_agg_softmax(const uint4* __restrict__ zb_f8,
                                  const float* __restrict__ r_f32,
                                  const int* __restrict__ rowstart,
                                  const int* __restrict__ csr_src,
                                  float* __restrict__ out) {
    int node = blockIdx.x * 4 + (threadIdx.x >> 6);
    int lane = threadIdx.x & 63;
    if (node >= N_NODES) return;
    int s0 = rowstart[node], s1 = rowstart[node + 1];
    int chunk = lane & 3, esel = lane >> 2;
    float acc[16];
    #pragma unroll
    for (int k = 0; k < 16; ++k) acc[k] = 0.f;
    for (int b = s0; b < s1; b += 64) {
        int m = min(64, s1 - b);
        int idx = (lane < m) ? csr_src[b + lane] : 0;
        int j = 0;
        for (; j + 32 <= m; j += 32) {
            int i0 = __shfl(idx, j + esel, 64);
            int i1 = __shfl(idx, j + 16 + esel, 64);
            uint4 v0 = zb_f8[(size_t)i0 * 4 + chunk];
            uint4 v1 = zb_f8[(size_t)i1 * 4 + chunk];
            acc_fp8x16(v0, acc);
            acc_fp8x16(v1, acc);
        }
        for (; j < m; j += 16) {
            int e = j + esel;
            int s = __shfl(idx, min(e, m - 1), 64);
            if (e < m) {
                uint4 v = zb_f8[(size_t)s * 4 + chunk];
                acc_fp8x16(v, acc);
            }
        }
    }
    float inv = 1.0f / fmaxf((float)(s1 - s0), 1.0f);
    #pragma unroll
    for (int k = 0; k < 16; ++k) {
        acc[k] += __shfl_xor(acc[k], 4, 64);
        acc[k] += __shfl_xor(acc[k], 8, 64);
        acc[k] += __shfl_xor(acc[k], 16, 64);
        acc[k] += __shfl_xor(acc[k], 32, 64);
    }
    // lanes 0..3: h = mean + r for dims chunk*16..+15
    float h[16];
    {
        const float4* rp = (const float4*)(r_f32 + (size_t)node * 64 + chunk * 16);
        #pragma unroll
        for (int q = 0; q < 4; ++q) {
            float4 rv = rp[q];
            h[q * 4 + 0] = acc[q * 4 + 0] * inv + rv.x;
            h[q * 4 + 1] = acc[q * 4 + 1] * inv + rv.y;
            h[q * 4 + 2] = acc[q * 4 + 2] * inv + rv.z;
            h[q * 4 + 3] = acc[q * 4 + 3] * inv + rv.w;
        }
    }
    float mx = h[0];
    #pragma unroll
    for (int k = 1; k < 16; ++k) mx = fmaxf(mx, h[k]);
    mx = fmaxf(mx, __shfl_xor(mx, 1, 64));
    mx = fmaxf(mx, __shfl_xor(mx, 2, 64));
    float s = 0.f;
    #pragma unroll
    for (int k = 0; k < 16; ++k) s += expf(h[k] - mx);
    s += __shfl_xor(s, 1, 64);
    s += __shfl_xor(s, 2, 64);
    float lse = mx + logf(s);
    if (lane < 4) {
        float4* o0 = (float4*)(out + (size_t)node * 64 + chunk * 16);
        float4* o1 = (float4*)(out + (size_t)N_NODES * 64 + (size_t)node * 64 + chunk * 16);
        #pragma unroll
        for (int q = 0; q < 4; ++q) {
            float4 a = {h[q * 4 + 0] - lse, h[q * 4 + 1] - lse,
                        h[q * 4 + 2] - lse, h[q * 4 + 3] - lse};
            float4 c = {h[q * 4 + 0], h[q * 4 + 1], h[q * 4 + 2], h[q * 4 + 3]};
            o0[q] = a; o1[q] = c;
        }
    }
}

extern "C" void kernel_launch(void* const* d_in, const int* in_sizes, int n_in,
                              void* d_out, int out_size, void* d_ws, size_t ws_size,
                              hipStream_t stream) {
    const float* x  = (const float*)d_in[0];
    const int* ei   = (const int*)d_in[1];
    const float* Wl0 = (const float*)d_in[2];
    const float* Wr0 = (const float*)d_in[3];
    const float* b0  = (const float*)d_in[4];
    const float* Wl1 = (const float*)d_in[5];
    const float* Wr1 = (const float*)d_in[6];
    const float* b1  = (const float*)d_in[7];
    const float* Wl2 = (const float*)d_in[8];
    const float* Wr2 = (const float*)d_in[9];
    const float* b2  = (const float*)d_in[10];
    float* out = (float*)d_out;

    char* ws = (char*)d_ws;
    int* cnt      = (int*)(ws + 0x000000);
    int* rowstart = (int*)(ws + 0x040000);
    int* cursor   = (int*)(ws + 0x080000);
    int* csr_src  = (int*)(ws + 0x100000);            // 3.2 MB
    ushort_t* pk0 = (ushort_t*)(ws + 0x420000);       // 64 KB
    ushort_t* pk1 = (ushort_t*)(ws + 0x440000);       // 64 KB
    ushort_t* pkz = (ushort_t*)(ws + 0x460000);       // 32 KB
    ushort_t* x_bf = (ushort_t*)(ws + 0x0500000);     // 12.8 MB (root L0); dead after L0
    ushort_t* h1   = (ushort_t*)(ws + 0x1F00000);     // 12.8 MB bf16 (root L1)
    unsigned char* x_f8 = (unsigned char*)(ws + 0x2C00000);  // 6.4 MB
    unsigned char* h1_f8 = (unsigned char*)(ws + 0x3400000); // 6.4 MB
    unsigned char* z_f8  = (unsigned char*)(ws + 0x3C00000); // 3.2 MB
    float* r_f32 = (float*)(ws + 0x0500000);          // 12.8 MB, aliases x_bf (dead)

    // ---- prep: cvt (bf16 + fp8) + weight packs + zero cnt ----
    prep<<<6619, 256, 0, stream>>>(x, (uint_t*)x_bf, (uint_t*)x_f8,
                                   Wl0, Wr0, Wl1, Wr1, Wl2, Wr2,
                                   pk0, pk1, pkz, cnt);

    // ---- CSR build: count -> scan -> fill ----
    count_edges_mp<<<1024, 256, 0, stream>>>(ei, cnt);
    scan_all<<<SCAN_BLOCKS, 256, 0, stream>>>(cnt, rowstart, cursor);
    fill_csr_mp<<<1024, 256, 0, stream>>>(ei, cursor, csr_src);

    // ---- layer 0 fused: gather x_f8 + root x_bf -> h1 (bf16 + fp8) ----
    layer_fused<false><<<3125, 512, 0, stream>>>(
        (const uint4*)x_f8, x_bf, rowstart, csr_src, pk0, b0,
        nullptr, nullptr, h1, h1_f8, nullptr, nullptr);

    // ---- layers 1+2 fused: gather h1_f8 + root h1 -> (z_f8, r_f32) ----
    layer_fused<true><<<3125, 512, 0, stream>>>(
        (const uint4*)h1_f8, h1, rowstart, csr_src, pk1, b1,
        pkz, b2, nullptr, nullptr, z_f8, r_f32);

    // ---- final gather (16 edges/load, fp8) + log_softmax -> d_out ----
    final_agg_softmax<<<12500, 256, 0, stream>>>((const uint4*)z_f8, r_f32,
                                                 rowstart, csr_src, out);
}